// Round 12
// baseline (156.270 us; speedup 1.0000x reference)
//
#include <hip/hip_runtime.h>
#include <hip/hip_bf16.h>
#include <math.h>

#define B 4
#define L 2048
#define H 8
#define D 64
#define SK 40
#define U 40
#define JC 32          // j-chunks in k_ctx
#define JCL (L / JC)   // 64 j per chunk

// ws layout (bytes)
#define OFF_M     0                  // B*H*L floats = 262144 B
#define OFF_TOP   262144             // B*H*U ints  = 5120 B
#define OFF_T     270336             // B*H*U*L floats (E matrix) = 10485760 B
#define OFF_PART  10756096           // JC * B*H*U*D floats = 10485760 B
#define OFF_CSUM  21241856           // B*H*U*JC floats = 163840 B (end ~21.4 MB)

__device__ __forceinline__ float dot4(float4 a, float4 b) {
    return fmaf(a.x, b.x, fmaf(a.y, b.y, fmaf(a.z, b.z, a.w * b.w)));
}

// K1: M[b,h,q] = max_s dot(Q[bhq], K[bh,idx[q,s]]) - (1/L) * sum_s dot(...)
// FP32 ONLY: M feeds an ordering (top-k ranks index output rows); fp16 dot
// noise (~4e-3) exceeds adjacent-rank M gaps (~1e-3) and permutes rows
// (R9/R10 failed at absmax 2.25 from exactly this).
// Layout: wave = 1 query x 4 h (one hh half); lane = hp(2b) x c(4b, float4).
// idx row is wave-uniform -> preloaded via 10 int4 loads (no shuffle
// broadcast); all 40 K-row addresses known upfront -> deep VMEM pipelining.
// XCD-locality: blockIdx%8 == b*2+hh pins each (b, h-half) to one XCD whose
// K working set is 2 MB < 4 MB L2. Per sample the wave reads 1 KB contiguous.
__global__ __launch_bounds__(256) void k_msamp(const float* __restrict__ Q,
                                               const float* __restrict__ K,
                                               const int* __restrict__ idx,
                                               float* __restrict__ M) {
    int g  = blockIdx.x & 7;        // = b*2 + hh  (XCD id under %8 round-robin)
    int b  = g >> 1;
    int hh = g & 1;
    int t  = threadIdx.x;
    int wave = t >> 6;
    int lane = t & 63;
    int hp = lane >> 4;             // h' within half (0..3)
    int c  = lane & 15;             // float4 chunk of D
    int h  = hh * 4 + hp;
    int q  = (blockIdx.x >> 3) * 4 + wave;

    float4 q4 = *((const float4*)(Q + (size_t)((b * L + q) * H + h) * D) + c);

    // preload all 40 sample indices (wave-uniform row, 160 B, 16B-aligned)
    const int4* ip4 = (const int4*)(idx + q * SK);
    int4 kv[10];
#pragma unroll
    for (int i = 0; i < 10; ++i) kv[i] = ip4[i];

    const float* kbase = K + (size_t)b * L * H * D + (size_t)h * D + c * 4;

    float vmax = -__builtin_inff();
    float vsum = 0.f;
#pragma unroll
    for (int i = 0; i < 10; ++i) {
        int ks0 = kv[i].x, ks1 = kv[i].y, ks2 = kv[i].z, ks3 = kv[i].w;
        int ksa[4] = {ks0, ks1, ks2, ks3};
#pragma unroll
        for (int j = 0; j < 4; ++j) {
            float4 k4 = *(const float4*)(kbase + (size_t)ksa[j] * (H * D));
            float d4v = dot4(q4, k4);
            // reduce across the 16 c-lanes of this h group
            d4v += __shfl_xor(d4v, 1, 64);
            d4v += __shfl_xor(d4v, 2, 64);
            d4v += __shfl_xor(d4v, 4, 64);
            d4v += __shfl_xor(d4v, 8, 64);
            vmax = fmaxf(vmax, d4v);
            vsum += d4v;
        }
    }
    if (c == 0) M[(size_t)(b * H + h) * L + q] = vmax - vsum * (1.0f / (float)L);
}

// K2: top-U per (b,h): min-max-normalized 256-bin select + exact candidate
// ranking. Order: value descending, ties -> lowest index (== jax.lax.top_k).
__global__ __launch_bounds__(256) void k_topk(const float* __restrict__ M,
                                              int* __restrict__ top) {
    __shared__ unsigned long long cand[L];    // worst-case candidates, 16 KB
    __shared__ unsigned int bins[256];
    __shared__ unsigned int red[256];
    __shared__ int cnt2;

    int bh = blockIdx.x;
    int tid = threadIdx.x;
    const float* m = M + (size_t)bh * L;

    bins[tid] = 0;
    if (tid == 0) cnt2 = 0;

    const float4* m4 = (const float4*)(m + tid * 8);
    float4 fa = m4[0], fb = m4[1];
    float f8[8] = {fa.x, fa.y, fa.z, fa.w, fb.x, fb.y, fb.z, fb.w};
    unsigned int u8[8];
    unsigned int umin = 0xFFFFFFFFu, umax = 0u;
#pragma unroll
    for (int e = 0; e < 8; ++e) {
        unsigned int bits = __float_as_uint(f8[e]);
        unsigned int u = (bits & 0x80000000u) ? ~bits : (bits | 0x80000000u);
        u8[e] = u;
        umin = min(umin, u);
        umax = max(umax, u);
    }
    red[tid] = umin;
    __syncthreads();
    for (int s = 128; s; s >>= 1) {
        if (tid < s) red[tid] = min(red[tid], red[tid + s]);
        __syncthreads();
    }
    unsigned int kmin = red[0];
    __syncthreads();
    red[tid] = umax;
    __syncthreads();
    for (int s = 128; s; s >>= 1) {
        if (tid < s) red[tid] = max(red[tid], red[tid + s]);
        __syncthreads();
    }
    unsigned int kmax = red[0];
    __syncthreads();

    unsigned int range = kmax - kmin;
    if (range == 0u) {
        if (tid < U) top[bh * U + tid] = tid;
        return;
    }
    int hb = 31 - __clz(range);
    int shift = (hb > 7) ? (hb - 7) : 0;

#pragma unroll
    for (int e = 0; e < 8; ++e) {
        unsigned int bin = (u8[e] - kmin) >> shift;
        atomicAdd(&bins[bin], 1u);
    }
    __syncthreads();

    red[tid] = bins[tid];
    __syncthreads();
    for (int s = 1; s < 256; s <<= 1) {
        unsigned int add = (tid + s < 256) ? red[tid + s] : 0u;
        __syncthreads();
        red[tid] += add;
        __syncthreads();
    }
    int cnt = __syncthreads_count(red[tid] >= U);
    unsigned int t = (unsigned int)(cnt - 1);

#pragma unroll
    for (int e = 0; e < 8; ++e) {
        unsigned int u = u8[e];
        if (((u - kmin) >> shift) >= t) {
            int pos = atomicAdd(&cnt2, 1);
            int i = tid * 8 + e;
            cand[pos] = ((unsigned long long)u << 11) | (unsigned long long)(2047 - i);
        }
    }
    __syncthreads();
    int C = cnt2;

    for (int j = tid; j < C; j += 256) {
        unsigned long long kj = cand[j];
        int r = 0;
        for (int kk = 0; kk < C; ++kk) r += (cand[kk] > kj);
        if (r < U) top[bh * U + r] = 2047 - (int)(kj & 0x7FFull);
    }
}

// K3a (fp32): E[bh,u,k] = exp(0.125 * dot(Q[bh,top[u]], K[bh,k])) — no
// max-sub needed (|score| <~ 6, fp32-safe; softmax normalization in k_red).
// Also emits csum[bh][u][jc] = sum of E over each 64-col chunk.
__global__ __launch_bounds__(256) void k_scores(const float* __restrict__ Q,
                                                const float* __restrict__ K,
                                                const int* __restrict__ top,
                                                float* __restrict__ T,
                                                float* __restrict__ csum) {
    __shared__ float4 sQ4[U * 16];   // 40 rows x 64 floats = 10 KB
    int bh = blockIdx.x >> 4;        // 16 k-chunks of 128
    int kc = blockIdx.x & 15;
    int b = bh >> 3, h = bh & (H - 1);
    int tid = threadIdx.x;
    int lane = tid & 63;
    int w = tid >> 6;

    for (int i = tid; i < U * 16; i += 256) {
        int u = i >> 4, c = i & 15;
        int qidx = top[bh * U + u];
        sQ4[i] = *((const float4*)(Q + (size_t)((b * L + qidx) * H + h) * D) + c);
    }

    int k0 = kc * 128 + lane;
    const float4* kr0 = (const float4*)(K + (size_t)((b * L + k0) * H + h) * D);
    const float4* kr1 = (const float4*)(K + (size_t)((b * L + k0 + 64) * H + h) * D);
    float4 kv0[16], kv1[16];
#pragma unroll
    for (int i = 0; i < 16; ++i) { kv0[i] = kr0[i]; kv1[i] = kr1[i]; }
    __syncthreads();

    float* Tb = T + (size_t)bh * U * L;
    for (int uu = 0; uu < 10; ++uu) {
        int u = w * 10 + uu;
        float s0 = 0.f, s1 = 0.f;
#pragma unroll
        for (int i = 0; i < 16; ++i) {
            float4 q4 = sQ4[u * 16 + i];   // broadcast LDS read
            s0 += dot4(q4, kv0[i]);
            s1 += dot4(q4, kv1[i]);
        }
        float e0 = __expf(s0 * 0.125f);
        float e1 = __expf(s1 * 0.125f);
        Tb[(size_t)u * L + k0]      = e0;
        Tb[(size_t)u * L + k0 + 64] = e1;
        float c0 = e0, c1 = e1;
#pragma unroll
        for (int o = 1; o < 64; o <<= 1) {
            c0 += __shfl_xor(c0, o, 64);
            c1 += __shfl_xor(c1, o, 64);
        }
        if (lane == 0) {
            csum[((size_t)bh * U + u) * JC + 2 * kc]     = c0;
            csum[((size_t)bh * U + u) * JC + 2 * kc + 1] = c1;
        }
    }
}

// K3c: part[jc,bh,u,d] = sum_{j in chunk jc} Tsuf[u,j] * V[b,j,h,d] where
// Tsuf[u,j] = within-chunk inclusive suffix of E + tail (computed inline
// from csum: sum of chunks beyond jc).
__global__ __launch_bounds__(256) void k_ctx(const float* __restrict__ V,
                                             const float* __restrict__ E,
                                             const float* __restrict__ csum,
                                             float* __restrict__ part) {
    __shared__ float sT[U][JCL];            // 40 x 64 floats = 10 KB
    int bh = blockIdx.x >> 5;               // JC = 32 chunks
    int jc = blockIdx.x & 31;
    int b = bh >> 3, h = bh & (H - 1);
    int tid = threadIdx.x;
    int w = tid >> 6;                       // wave: u in [10w, 10w+10)
    int lane = tid & 63;
    int j2 = lane >> 4;                     // 0..3 j-subgroup
    int d4 = lane & 15;                     // float4 index along d
    int jlane = lane & 31;

    const float* Eg = E + (size_t)bh * U * L + jc * JCL;
#pragma unroll
    for (int r = 0; r < 10; ++r) {
        int u = w * 10 + r;
        // tail = sum of csum chunks beyond jc (both 32-lane halves compute it)
        float cv = csum[((size_t)bh * U + u) * JC + jlane];
        float tv = (jlane > jc) ? cv : 0.f;
        tv += __shfl_xor(tv, 1, 64);
        tv += __shfl_xor(tv, 2, 64);
        tv += __shfl_xor(tv, 4, 64);
        tv += __shfl_xor(tv, 8, 64);
        tv += __shfl_xor(tv, 16, 64);
        float v = Eg[(size_t)u * L + lane];
        // 6-step inclusive suffix scan across the wave
#pragma unroll
        for (int s = 1; s < 64; s <<= 1) {
            float o = __shfl_down(v, s, 64);
            v += (lane + s < 64) ? o : 0.f;
        }
        sT[u][lane] = v + tv;
    }
    __syncthreads();

    float4 acc[10];
#pragma unroll
    for (int uu = 0; uu < 10; ++uu) acc[uu] = make_float4(0.f, 0.f, 0.f, 0.f);

    const float* Vb = V + (size_t)(b * L) * (H * D) + (size_t)h * D + d4 * 4;
#pragma unroll 4
    for (int it = 0; it < JCL / 4; ++it) {
        int j = it * 4 + j2;
        float4 v4 = *(const float4*)(Vb + (size_t)(jc * JCL + j) * (H * D));
#pragma unroll
        for (int uu = 0; uu < 10; ++uu) {
            float tj = sT[w * 10 + uu][j];   // broadcast LDS read
            acc[uu].x = fmaf(tj, v4.x, acc[uu].x);
            acc[uu].y = fmaf(tj, v4.y, acc[uu].y);
            acc[uu].z = fmaf(tj, v4.z, acc[uu].z);
            acc[uu].w = fmaf(tj, v4.w, acc[uu].w);
        }
    }

    float* po = part + ((size_t)jc * (B * H) + bh) * (U * D);
#pragma unroll
    for (int uu = 0; uu < 10; ++uu) {
        float4 a = acc[uu];
        a.x += __shfl_xor(a.x, 16, 64); a.y += __shfl_xor(a.y, 16, 64);
        a.z += __shfl_xor(a.z, 16, 64); a.w += __shfl_xor(a.w, 16, 64);
        a.x += __shfl_xor(a.x, 32, 64); a.y += __shfl_xor(a.y, 32, 64);
        a.z += __shfl_xor(a.z, 32, 64); a.w += __shfl_xor(a.w, 32, 64);
        if (j2 == 0) *(float4*)(po + (w * 10 + uu) * D + d4 * 4) = a;
    }
}

// final reduce over the JC j-chunks + softmax normalization (denominator
// computed from csum inline; block covers 4 u-rows of one bh)
__global__ __launch_bounds__(256) void k_red(const float* __restrict__ part,
                                             const float* __restrict__ csum,
                                             float* __restrict__ out) {
    __shared__ float sden[4];
    int o = blockIdx.x * 256 + threadIdx.x;
    int bh = o / (U * D);
    int rest = o - bh * (U * D);
    int u = rest >> 6;
    int tid = threadIdx.x;
    int ubase = ((blockIdx.x * 256) % (U * D)) >> 6;

    if (tid < 128) {
        int ul = tid >> 5, j = tid & 31;
        float v = csum[((size_t)bh * U + ubase + ul) * JC + j];
        v += __shfl_xor(v, 1, 64);
        v += __shfl_xor(v, 2, 64);
        v += __shfl_xor(v, 4, 64);
        v += __shfl_xor(v, 8, 64);
        v += __shfl_xor(v, 16, 64);
        if (j == 0) sden[ul] = v;
    }
    __syncthreads();

    float s = 0.f;
#pragma unroll
    for (int jc = 0; jc < JC; ++jc)
        s += part[(size_t)(jc * (B * H) + bh) * (U * D) + rest];
    out[o] = s / sden[u - ubase];
}

extern "C" void kernel_launch(void* const* d_in, const int* in_sizes, int n_in,
                              void* d_out, int out_size, void* d_ws, size_t ws_size,
                              hipStream_t stream) {
    const float* Q  = (const float*)d_in[0];
    const float* K  = (const float*)d_in[1];
    const float* V  = (const float*)d_in[2];
    const int* idx  = (const int*)d_in[3];
    float* out = (float*)d_out;

    float* M    = (float*)((char*)d_ws + OFF_M);
    int*   top  = (int*)  ((char*)d_ws + OFF_TOP);
    float* T    = (float*)((char*)d_ws + OFF_T);
    float* part = (float*)((char*)d_ws + OFF_PART);
    float* csum = (float*)((char*)d_ws + OFF_CSUM);

    // K1: 512 q-quads x 8 (b,hh) groups; %8 pins (b,hh) to an XCD
    k_msamp<<<(L / 4) * 8, 256, 0, stream>>>(Q, K, idx, M);
    k_topk<<<B * H, 256, 0, stream>>>(M, top);
    k_scores<<<B * H * 16, 256, 0, stream>>>(Q, K, top, T, csum);
    k_ctx<<<B * H * JC, 256, 0, stream>>>(V, T, csum, part);
    k_red<<<(B * H * U * D) / 256, 256, 0, stream>>>(part, csum, out);
}

// Round 13
// 149.505 us; speedup vs baseline: 1.0453x; 1.0453x over previous
//
#include <hip/hip_runtime.h>
#include <hip/hip_bf16.h>
#include <math.h>

#define B 4
#define L 2048
#define H 8
#define D 64
#define SK 40
#define U 40
#define JC 32          // j-chunks in k_ctx
#define JCL (L / JC)   // 64 j per chunk

// ws layout (bytes)
#define OFF_M     0                  // B*H*L floats = 262144 B
#define OFF_TOP   262144             // B*H*U ints  = 5120 B
#define OFF_T     270336             // B*H*U*L floats (E matrix) = 10485760 B
#define OFF_PART  10756096           // JC * B*H*U*D floats = 10485760 B
#define OFF_CSUM  21241856           // B*H*U*JC floats = 163840 B (end ~21.4 MB)

__device__ __forceinline__ float dot4(float4 a, float4 b) {
    return fmaf(a.x, b.x, fmaf(a.y, b.y, fmaf(a.z, b.z, a.w * b.w)));
}

// K1: M[b,h,q] = max_s dot(Q[bhq], K[bh,idx[q,s]]) - (1/L) * sum_s dot(...)
// FP32 ONLY: M feeds an ordering (top-k ranks index output rows); fp16 dot
// noise (~4e-3) exceeds adjacent-rank M gaps (~1e-3) and permutes rows
// (R9/R10 failed at absmax 2.25 from exactly this).
// Best-measured coding (R11): wave = 2 queries; lane = qp*32 + hp*8 + c8;
// idx preloaded to regs and broadcast via shuffles. Three structural
// variants (R6/R11/R12) all land 38-44 us -> L2 gather-bandwidth ceiling
// (~16 TB/s effective for 1 KB random bursts); traffic is irreducible
// (disjoint per-q sample sets -> no tiling reuse possible).
// XCD-locality: blockIdx%8 == b*2+hh pins each (b, h-half) to one XCD whose
// K working set is 2.1 MB < 4 MB L2.
__global__ __launch_bounds__(256) void k_msamp(const float* __restrict__ Q,
                                               const float* __restrict__ K,
                                               const int* __restrict__ idx,
                                               float* __restrict__ M) {
    int g  = blockIdx.x & 7;        // = b*2 + hh  (XCD id under %8 round-robin)
    int b  = g >> 1;
    int hh = g & 1;
    int t  = threadIdx.x;
    int wave = t >> 6;
    int lane = t & 63;
    int qp = lane >> 5;             // 0/1: which query of this wave
    int hp = (lane >> 3) & 3;       // h' within half
    int c  = lane & 7;              // 8-float chunk of D
    int h  = hh * 4 + hp;
    int q  = (blockIdx.x >> 3) * 8 + wave * 2 + qp;

    const float* qrow = Q + (size_t)((b * L + q) * H + h) * D + c * 8;
    float4 qa = *(const float4*)qrow;
    float4 qb = *(const float4*)(qrow + 4);

    int s1 = lane & 31;
    int v1 = idx[q * SK + s1];
    int s2 = 32 + s1; if (s2 > SK - 1) s2 = SK - 1;   // clamp (dup, unused)
    int v2 = idx[q * SK + s2];

    const float* kbase = K + (size_t)b * L * H * D + (size_t)h * D + c * 8;

    float vmax = -__builtin_inff();
    float vsum = 0.f;
#pragma unroll 8
    for (int s = 0; s < SK; ++s) {
        int kidx = (s < 32) ? __shfl(v1, qp * 32 + s, 64)
                            : __shfl(v2, qp * 32 + (s - 32), 64);
        const float* kp = kbase + (size_t)kidx * (H * D);
        float4 ka = *(const float4*)kp;
        float4 kb = *(const float4*)(kp + 4);
        float d8 = dot4(qa, ka) + dot4(qb, kb);
        d8 += __shfl_xor(d8, 1, 64);
        d8 += __shfl_xor(d8, 2, 64);
        d8 += __shfl_xor(d8, 4, 64);
        vmax = fmaxf(vmax, d8);
        vsum += d8;
    }
    if (c == 0) M[(size_t)(b * H + h) * L + q] = vmax - vsum * (1.0f / (float)L);
}

// K2: top-U per (b,h): min-max-normalized 256-bin select + exact candidate
// ranking. Order: value descending, ties -> lowest index (== jax.lax.top_k).
__global__ __launch_bounds__(256) void k_topk(const float* __restrict__ M,
                                              int* __restrict__ top) {
    __shared__ unsigned long long cand[L];    // worst-case candidates, 16 KB
    __shared__ unsigned int bins[256];
    __shared__ unsigned int red[256];
    __shared__ int cnt2;

    int bh = blockIdx.x;
    int tid = threadIdx.x;
    const float* m = M + (size_t)bh * L;

    bins[tid] = 0;
    if (tid == 0) cnt2 = 0;

    const float4* m4 = (const float4*)(m + tid * 8);
    float4 fa = m4[0], fb = m4[1];
    float f8[8] = {fa.x, fa.y, fa.z, fa.w, fb.x, fb.y, fb.z, fb.w};
    unsigned int u8[8];
    unsigned int umin = 0xFFFFFFFFu, umax = 0u;
#pragma unroll
    for (int e = 0; e < 8; ++e) {
        unsigned int bits = __float_as_uint(f8[e]);
        unsigned int u = (bits & 0x80000000u) ? ~bits : (bits | 0x80000000u);
        u8[e] = u;
        umin = min(umin, u);
        umax = max(umax, u);
    }
    red[tid] = umin;
    __syncthreads();
    for (int s = 128; s; s >>= 1) {
        if (tid < s) red[tid] = min(red[tid], red[tid + s]);
        __syncthreads();
    }
    unsigned int kmin = red[0];
    __syncthreads();
    red[tid] = umax;
    __syncthreads();
    for (int s = 128; s; s >>= 1) {
        if (tid < s) red[tid] = max(red[tid], red[tid + s]);
        __syncthreads();
    }
    unsigned int kmax = red[0];
    __syncthreads();

    unsigned int range = kmax - kmin;
    if (range == 0u) {
        if (tid < U) top[bh * U + tid] = tid;
        return;
    }
    int hb = 31 - __clz(range);
    int shift = (hb > 7) ? (hb - 7) : 0;

#pragma unroll
    for (int e = 0; e < 8; ++e) {
        unsigned int bin = (u8[e] - kmin) >> shift;
        atomicAdd(&bins[bin], 1u);
    }
    __syncthreads();

    red[tid] = bins[tid];
    __syncthreads();
    for (int s = 1; s < 256; s <<= 1) {
        unsigned int add = (tid + s < 256) ? red[tid + s] : 0u;
        __syncthreads();
        red[tid] += add;
        __syncthreads();
    }
    int cnt = __syncthreads_count(red[tid] >= U);
    unsigned int t = (unsigned int)(cnt - 1);

#pragma unroll
    for (int e = 0; e < 8; ++e) {
        unsigned int u = u8[e];
        if (((u - kmin) >> shift) >= t) {
            int pos = atomicAdd(&cnt2, 1);
            int i = tid * 8 + e;
            cand[pos] = ((unsigned long long)u << 11) | (unsigned long long)(2047 - i);
        }
    }
    __syncthreads();
    int C = cnt2;

    for (int j = tid; j < C; j += 256) {
        unsigned long long kj = cand[j];
        int r = 0;
        for (int kk = 0; kk < C; ++kk) r += (cand[kk] > kj);
        if (r < U) top[bh * U + r] = 2047 - (int)(kj & 0x7FFull);
    }
}

// K3a (fp32): E[bh,u,k] = exp(0.125 * dot(Q[bh,top[u]], K[bh,k])) — no
// max-sub needed (|score| <~ 6, fp32-safe; softmax normalization in k_red).
// Also emits csum[bh][u][jc] = sum of E over each 64-col chunk.
__global__ __launch_bounds__(256) void k_scores(const float* __restrict__ Q,
                                                const float* __restrict__ K,
                                                const int* __restrict__ top,
                                                float* __restrict__ T,
                                                float* __restrict__ csum) {
    __shared__ float4 sQ4[U * 16];   // 40 rows x 64 floats = 10 KB
    int bh = blockIdx.x >> 4;        // 16 k-chunks of 128
    int kc = blockIdx.x & 15;
    int b = bh >> 3, h = bh & (H - 1);
    int tid = threadIdx.x;
    int lane = tid & 63;
    int w = tid >> 6;

    for (int i = tid; i < U * 16; i += 256) {
        int u = i >> 4, c = i & 15;
        int qidx = top[bh * U + u];
        sQ4[i] = *((const float4*)(Q + (size_t)((b * L + qidx) * H + h) * D) + c);
    }

    int k0 = kc * 128 + lane;
    const float4* kr0 = (const float4*)(K + (size_t)((b * L + k0) * H + h) * D);
    const float4* kr1 = (const float4*)(K + (size_t)((b * L + k0 + 64) * H + h) * D);
    float4 kv0[16], kv1[16];
#pragma unroll
    for (int i = 0; i < 16; ++i) { kv0[i] = kr0[i]; kv1[i] = kr1[i]; }
    __syncthreads();

    float* Tb = T + (size_t)bh * U * L;
    for (int uu = 0; uu < 10; ++uu) {
        int u = w * 10 + uu;
        float s0 = 0.f, s1 = 0.f;
#pragma unroll
        for (int i = 0; i < 16; ++i) {
            float4 q4 = sQ4[u * 16 + i];   // broadcast LDS read
            s0 += dot4(q4, kv0[i]);
            s1 += dot4(q4, kv1[i]);
        }
        float e0 = __expf(s0 * 0.125f);
        float e1 = __expf(s1 * 0.125f);
        Tb[(size_t)u * L + k0]      = e0;
        Tb[(size_t)u * L + k0 + 64] = e1;
        float c0 = e0, c1 = e1;
#pragma unroll
        for (int o = 1; o < 64; o <<= 1) {
            c0 += __shfl_xor(c0, o, 64);
            c1 += __shfl_xor(c1, o, 64);
        }
        if (lane == 0) {
            csum[((size_t)bh * U + u) * JC + 2 * kc]     = c0;
            csum[((size_t)bh * U + u) * JC + 2 * kc + 1] = c1;
        }
    }
}

// K3c: part[jc,bh,u,d] = sum_{j in chunk jc} Tsuf[u,j] * V[b,j,h,d] where
// Tsuf[u,j] = within-chunk inclusive suffix of E + tail (computed inline
// from csum: sum of chunks beyond jc).
__global__ __launch_bounds__(256) void k_ctx(const float* __restrict__ V,
                                             const float* __restrict__ E,
                                             const float* __restrict__ csum,
                                             float* __restrict__ part) {
    __shared__ float sT[U][JCL];            // 40 x 64 floats = 10 KB
    int bh = blockIdx.x >> 5;               // JC = 32 chunks
    int jc = blockIdx.x & 31;
    int b = bh >> 3, h = bh & (H - 1);
    int tid = threadIdx.x;
    int w = tid >> 6;                       // wave: u in [10w, 10w+10)
    int lane = tid & 63;
    int j2 = lane >> 4;                     // 0..3 j-subgroup
    int d4 = lane & 15;                     // float4 index along d
    int jlane = lane & 31;

    const float* Eg = E + (size_t)bh * U * L + jc * JCL;
#pragma unroll
    for (int r = 0; r < 10; ++r) {
        int u = w * 10 + r;
        // tail = sum of csum chunks beyond jc (both 32-lane halves compute it)
        float cv = csum[((size_t)bh * U + u) * JC + jlane];
        float tv = (jlane > jc) ? cv : 0.f;
        tv += __shfl_xor(tv, 1, 64);
        tv += __shfl_xor(tv, 2, 64);
        tv += __shfl_xor(tv, 4, 64);
        tv += __shfl_xor(tv, 8, 64);
        tv += __shfl_xor(tv, 16, 64);
        float v = Eg[(size_t)u * L + lane];
        // 6-step inclusive suffix scan across the wave
#pragma unroll
        for (int s = 1; s < 64; s <<= 1) {
            float o = __shfl_down(v, s, 64);
            v += (lane + s < 64) ? o : 0.f;
        }
        sT[u][lane] = v + tv;
    }
    __syncthreads();

    float4 acc[10];
#pragma unroll
    for (int uu = 0; uu < 10; ++uu) acc[uu] = make_float4(0.f, 0.f, 0.f, 0.f);

    const float* Vb = V + (size_t)(b * L) * (H * D) + (size_t)h * D + d4 * 4;
#pragma unroll 4
    for (int it = 0; it < JCL / 4; ++it) {
        int j = it * 4 + j2;
        float4 v4 = *(const float4*)(Vb + (size_t)(jc * JCL + j) * (H * D));
#pragma unroll
        for (int uu = 0; uu < 10; ++uu) {
            float tj = sT[w * 10 + uu][j];   // broadcast LDS read
            acc[uu].x = fmaf(tj, v4.x, acc[uu].x);
            acc[uu].y = fmaf(tj, v4.y, acc[uu].y);
            acc[uu].z = fmaf(tj, v4.z, acc[uu].z);
            acc[uu].w = fmaf(tj, v4.w, acc[uu].w);
        }
    }

    float* po = part + ((size_t)jc * (B * H) + bh) * (U * D);
#pragma unroll
    for (int uu = 0; uu < 10; ++uu) {
        float4 a = acc[uu];
        a.x += __shfl_xor(a.x, 16, 64); a.y += __shfl_xor(a.y, 16, 64);
        a.z += __shfl_xor(a.z, 16, 64); a.w += __shfl_xor(a.w, 16, 64);
        a.x += __shfl_xor(a.x, 32, 64); a.y += __shfl_xor(a.y, 32, 64);
        a.z += __shfl_xor(a.z, 32, 64); a.w += __shfl_xor(a.w, 32, 64);
        if (j2 == 0) *(float4*)(po + (w * 10 + uu) * D + d4 * 4) = a;
    }
}

// final reduce over the JC j-chunks + softmax normalization (denominator
// computed from csum inline; block covers 4 u-rows of one bh)
__global__ __launch_bounds__(256) void k_red(const float* __restrict__ part,
                                             const float* __restrict__ csum,
                                             float* __restrict__ out) {
    __shared__ float sden[4];
    int o = blockIdx.x * 256 + threadIdx.x;
    int bh = o / (U * D);
    int rest = o - bh * (U * D);
    int u = rest >> 6;
    int tid = threadIdx.x;
    int ubase = ((blockIdx.x * 256) % (U * D)) >> 6;

    if (tid < 128) {
        int ul = tid >> 5, j = tid & 31;
        float v = csum[((size_t)bh * U + ubase + ul) * JC + j];
        v += __shfl_xor(v, 1, 64);
        v += __shfl_xor(v, 2, 64);
        v += __shfl_xor(v, 4, 64);
        v += __shfl_xor(v, 8, 64);
        v += __shfl_xor(v, 16, 64);
        if (j == 0) sden[ul] = v;
    }
    __syncthreads();

    float s = 0.f;
#pragma unroll
    for (int jc = 0; jc < JC; ++jc)
        s += part[(size_t)(jc * (B * H) + bh) * (U * D) + rest];
    out[o] = s / sden[u - ubase];
}

extern "C" void kernel_launch(void* const* d_in, const int* in_sizes, int n_in,
                              void* d_out, int out_size, void* d_ws, size_t ws_size,
                              hipStream_t stream) {
    const float* Q  = (const float*)d_in[0];
    const float* K  = (const float*)d_in[1];
    const float* V  = (const float*)d_in[2];
    const int* idx  = (const int*)d_in[3];
    float* out = (float*)d_out;

    float* M    = (float*)((char*)d_ws + OFF_M);
    int*   top  = (int*)  ((char*)d_ws + OFF_TOP);
    float* T    = (float*)((char*)d_ws + OFF_T);
    float* part = (float*)((char*)d_ws + OFF_PART);
    float* csum = (float*)((char*)d_ws + OFF_CSUM);

    // K1: 256 q-octets x 8 (b,hh) groups; %8 pins (b,hh) to an XCD
    k_msamp<<<(L / 8) * 8, 256, 0, stream>>>(Q, K, idx, M);
    k_topk<<<B * H, 256, 0, stream>>>(M, top);
    k_scores<<<B * H * 16, 256, 0, stream>>>(Q, K, top, T, csum);
    k_ctx<<<B * H * JC, 256, 0, stream>>>(V, T, csum, part);
    k_red<<<(B * H * U * D) / 256, 256, 0, stream>>>(part, csum, out);
}